// Round 5
// baseline (616.482 us; speedup 1.0000x reference)
//
#include <hip/hip_runtime.h>
#include <hip/hip_bf16.h>
#include <stdint.h>

#define B_SZ   128
#define D_SZ   3072
#define N_SZ   20000
#define NPAD   20480   // 313*64 score tiles (20032) < NPAD; 40 drift K-chunks * 512
#define BN     (B_SZ * NPAD)     // 2621440 elems
#define BD     (B_SZ * D_SZ)     // 393216 elems
#define KC_S   4                 // scores K-chunks (768 each)
#define KC_D   40                // drift K-chunks (512 each)

typedef __attribute__((ext_vector_type(8))) short          short8;
typedef __attribute__((ext_vector_type(4))) float          f32x4;

__device__ __forceinline__ unsigned short f2bf(float f) {
    unsigned u = __float_as_uint(f);
    u += 0x7FFFu + ((u >> 16) & 1u);   // round-to-nearest-even
    return (unsigned short)(u >> 16);
}
__device__ __forceinline__ float bf2f(unsigned short h) {
    return __uint_as_float(((unsigned)h) << 16);
}
// order-preserving float<->uint key for atomicMax over signed floats
__device__ __forceinline__ unsigned fkey_enc(float f) {
    unsigned b = __float_as_uint(f);
    return (b & 0x80000000u) ? ~b : (b | 0x80000000u);
}
__device__ __forceinline__ float fkey_dec(unsigned u) {
    return __uint_as_float((u & 0x80000000u) ? (u ^ 0x80000000u) : ~u);
}

__device__ __forceinline__ void gl_lds16(const void* g, void* l) {
    __builtin_amdgcn_global_load_lds(
        (const __attribute__((address_space(1))) void*)g,
        (__attribute__((address_space(3))) void*)l, 16, 0, 0);
}

// bank swizzle: 16B slot for (row r, k-quarter q) is q ^ ((r>>1)&3) -> 2-way
// aliasing only (free, m136); involution, applied at the global SOURCE of
// global_load_lds and again at the ds_read (both-sides rule).
__device__ __forceinline__ int swz(int r, int q) { return q ^ ((r >> 1) & 3); }

// ---------------- zero G2 + Mkey + L (20736 floats, contiguous) ------------
__global__ __launch_bounds__(256) void zero_small(float* __restrict__ p)
{
    p[blockIdx.x * 256 + threadIdx.x] = 0.f;   // grid 81: 81*256 = 20736
}

// ---------------- split x into bf16 hi/lo ----------------
__global__ __launch_bounds__(256) void prep_x(const float* __restrict__ x,
                                              unsigned short* __restrict__ xhi,
                                              unsigned short* __restrict__ xlo)
{
    int i = blockIdx.x * 256 + threadIdx.x;     // exactly 128*3072
    float v = x[i];
    unsigned short h = f2bf(v);
    xhi[i] = h;
    xlo[i] = f2bf(v - bf2f(h));
}

// ---------------- prep_g: gt -> Ghi/Glo [n][d], GhT [d][n], G2 -------------
// Pure streaming pass (read 246MB, write 378MB). Tile 64n x 64d per block;
// grid = 320*48 = 15360. Pad rows/cols (n >= 20000) written as exact zeros
// so downstream kernels need no clamps and MFMA pad contributions are 0.
__global__ __launch_bounds__(256) void prep_g(
        const float* __restrict__ gt,
        unsigned short* __restrict__ Ghi,
        unsigned short* __restrict__ Glo,
        unsigned short* __restrict__ GhT,
        float* __restrict__ G2)
{
    __shared__ unsigned short Lh[64][72];   // 64x64 hi tile, +8 pad
    const int tid = threadIdx.x;
    const int dt  = blockIdx.x % 48;
    const int ntl = blockIdx.x / 48;
    const int n0 = ntl * 64, d0 = dt * 64;
    const int r = tid >> 2, c4 = tid & 3;
    const int n = n0 + r;

    float v[16];
    if (n < N_SZ) {
        const float* gp = gt + (size_t)n * D_SZ + d0 + c4 * 16;
        #pragma unroll
        for (int i = 0; i < 4; i++) {
            f32x4 x = *(const f32x4*)(gp + i * 4);
            v[4*i+0] = x[0]; v[4*i+1] = x[1]; v[4*i+2] = x[2]; v[4*i+3] = x[3];
        }
    } else {
        #pragma unroll
        for (int j = 0; j < 16; j++) v[j] = 0.f;
    }

    short8 h0, h1, l0, l1;
    float g2 = 0.f;
    #pragma unroll
    for (int j = 0; j < 16; j++) {
        unsigned short h = f2bf(v[j]);
        unsigned short l = f2bf(v[j] - bf2f(h));
        if (j < 8) { h0[j] = (short)h; l0[j] = (short)l; }
        else       { h1[j-8] = (short)h; l1[j-8] = (short)l; }
        g2 += v[j] * v[j];
        Lh[r][c4 * 16 + j] = h;
    }
    size_t go = (size_t)n * D_SZ + d0 + c4 * 16;
    *(short8*)(Ghi + go)     = h0;  *(short8*)(Ghi + go + 8) = h1;
    *(short8*)(Glo + go)     = l0;  *(short8*)(Glo + go + 8) = l1;

    g2 += __shfl_xor(g2, 1);
    g2 += __shfl_xor(g2, 2);
    if (c4 == 0 && n < N_SZ) atomicAdd(&G2[n], g2);

    __syncthreads();

    // transposed hi: GhT[d][n]
    const int od = tid >> 2, oc4 = tid & 3;
    short8 t0, t1;
    #pragma unroll
    for (int j = 0; j < 8; j++) {
        t0[j] = (short)Lh[oc4 * 16 + j][od];
        t1[j] = (short)Lh[oc4 * 16 + 8 + j][od];
    }
    size_t to = (size_t)(d0 + od) * NPAD + n0 + oc4 * 16;
    *(short8*)(GhT + to)     = t0;
    *(short8*)(GhT + to + 8) = t1;
}

// ---------------- scores: XG_part[kc][b][n] = partial x.g -----------------
// grid = 313 n-tiles * 4 K-chunks = 1252. Tile M=128 x N=64, K 768 (24x32).
// Pure 2-operand bf16 GEMM: all 4 tiles staged via global_load_lds,
// TRIPLE-buffered (72KB), counted s_waitcnt vmcnt(6) + raw s_barrier --
// loads stay 2 phases in flight, never drained to 0 in the loop (T3/T4).
// split-precision: acc = xhi*ghi + xhi*glo + xlo*ghi  (fp32-accurate dot)
__global__ __launch_bounds__(256) void scores_kernel(
        const unsigned short* __restrict__ Ghi_g,
        const unsigned short* __restrict__ Glo_g,
        const unsigned short* __restrict__ xhi,
        const unsigned short* __restrict__ xlo,
        float* __restrict__ XG_part)
{
    __shared__ __align__(16) unsigned short Xhi_t[3][128 * 32];
    __shared__ __align__(16) unsigned short Xlo_t[3][128 * 32];
    __shared__ __align__(16) unsigned short Ghi_t[3][64 * 32];
    __shared__ __align__(16) unsigned short Glo_t[3][64 * 32];

    const int tid   = threadIdx.x;
    const int kc    = blockIdx.x & 3;        // K-chunk (4 x 768)
    const int nt    = blockIdx.x >> 2;       // n-tile (313)
    const int nbase = nt * 64;
    const int kcb   = kc * 768;

    const int lane = tid & 63;
    const int wave = tid >> 6;
    const int mh = wave & 1;      // M half (64 rows)
    const int nh = wave >> 1;     // N half (32 cols)
    const int lm = lane & 15;
    const int qd = lane >> 4;

    // X staging: 2 gl_lds per tile; source pre-swizzled at 16B granularity
    int xsrc[2], xdst[2];
    #pragma unroll
    for (int i = 0; i < 2; i++) {
        int o = (i * 256 + tid) * 16;
        int r = o >> 6;
        int j = (o >> 4) & 3;
        xdst[i] = o;
        xsrc[i] = r * D_SZ + kcb + swz(r, j) * 8;
    }
    // G staging: 1 gl_lds per tile (64x32 = 4KB)
    const int gr = tid >> 2, gs = tid & 3;
    const int gsrc = (nbase + gr) * D_SZ + kcb + swz(gr, gs) * 8;
    const int gdst = tid * 16;

    f32x4 acc[4][2];
    #pragma unroll
    for (int i = 0; i < 4; i++)
        #pragma unroll
        for (int j = 0; j < 2; j++)
            acc[i][j] = (f32x4){0.f, 0.f, 0.f, 0.f};

#define STAGE_S(kk, bb) do {                                              \
        int k0_ = (kk) * 32;                                              \
        gl_lds16(xhi   + xsrc[0] + k0_, (char*)Xhi_t[bb] + xdst[0]);      \
        gl_lds16(xhi   + xsrc[1] + k0_, (char*)Xhi_t[bb] + xdst[1]);      \
        gl_lds16(xlo   + xsrc[0] + k0_, (char*)Xlo_t[bb] + xdst[0]);      \
        gl_lds16(xlo   + xsrc[1] + k0_, (char*)Xlo_t[bb] + xdst[1]);      \
        gl_lds16(Ghi_g + gsrc + k0_,    (char*)Ghi_t[bb] + gdst);         \
        gl_lds16(Glo_g + gsrc + k0_,    (char*)Glo_t[bb] + gdst);         \
    } while (0)

    STAGE_S(0, 0);
    STAGE_S(1, 1);

    for (int t = 0; t < 24; t++) {
        // wait for step t's 6 loads (allow step t+1's 6 to stay in flight)
        if (t < 23) asm volatile("s_waitcnt vmcnt(6) lgkmcnt(0)" ::: "memory");
        else        asm volatile("s_waitcnt vmcnt(0) lgkmcnt(0)" ::: "memory");
        __builtin_amdgcn_sched_barrier(0);
        __builtin_amdgcn_s_barrier();
        __builtin_amdgcn_sched_barrier(0);

        const int bc = t % 3;
        if (t < 22) { STAGE_S(t + 2, (t + 2) % 3); }

        short8 bhi[2], blo[2];
        #pragma unroll
        for (int ni = 0; ni < 2; ni++) {
            int r = nh * 32 + ni * 16 + lm;
            int sl = r * 32 + swz(r, qd) * 8;
            bhi[ni] = *(short8*)&Ghi_t[bc][sl];
            blo[ni] = *(short8*)&Glo_t[bc][sl];
        }
        #pragma unroll
        for (int mi = 0; mi < 4; mi++) {
            int r = mh * 64 + mi * 16 + lm;
            int sl = r * 32 + swz(r, qd) * 8;
            short8 ahi = *(short8*)&Xhi_t[bc][sl];
            short8 alo = *(short8*)&Xlo_t[bc][sl];
            #pragma unroll
            for (int ni = 0; ni < 2; ni++) {
                acc[mi][ni] = __builtin_amdgcn_mfma_f32_16x16x32_bf16(ahi, bhi[ni], acc[mi][ni], 0, 0, 0);
                acc[mi][ni] = __builtin_amdgcn_mfma_f32_16x16x32_bf16(ahi, blo[ni], acc[mi][ni], 0, 0, 0);
                acc[mi][ni] = __builtin_amdgcn_mfma_f32_16x16x32_bf16(alo, bhi[ni], acc[mi][ni], 0, 0, 0);
            }
        }
    }
#undef STAGE_S

    // epilogue: C/D layout col=lane&15, row=qd*4+i ; plain store of partial
    float* XGp = XG_part + (size_t)kc * BN;
    #pragma unroll
    for (int mi = 0; mi < 4; mi++) {
        #pragma unroll
        for (int ni = 0; ni < 2; ni++) {
            int ncol = nh * 32 + ni * 16 + lm;
            int ng = nbase + ncol;
            if (ng < N_SZ) {
                #pragma unroll
                for (int i = 0; i < 4; i++) {
                    int m = mh * 64 + mi * 16 + qd * 4 + i;
                    XGp[(size_t)m * NPAD + ng] = acc[mi][ni][i];
                }
            }
        }
    }
}

// ---------------- sum4max: XG = sum_kc XG_part[kc]; fused row-max ---------
// grid 2560 = 128 b * 20 chunks of 1024 -> each block lies inside one b row.
__global__ __launch_bounds__(256) void sum4max(
        const float* __restrict__ XG_part, const float* __restrict__ G2,
        const float* __restrict__ tarr, float* __restrict__ XG,
        unsigned* __restrict__ Mkey)
{
    const int tid = threadIdx.x;
    const int b = blockIdx.x / 20;
    const int i = (blockIdx.x * 256 + tid) * 4;
    __shared__ float wred[4];

    f32x4 s = (f32x4){0.f, 0.f, 0.f, 0.f};
    #pragma unroll
    for (int kc = 0; kc < KC_S; kc++)
        s += *(const f32x4*)(XG_part + (size_t)kc * BN + i);
    *(f32x4*)(XG + i) = s;

    float tt  = tarr[b] / 999.0f;
    float sig = 1.0f - tt;
    float inv = 1.0f / (sig * sig);
    float c1 = tt * inv, c2 = 0.5f * tt * tt * inv;
    int n = i - b * NPAD;

    float mx = -3.402823466e+38f;
    #pragma unroll
    for (int j = 0; j < 4; j++)
        if (n + j < N_SZ) mx = fmaxf(mx, c1 * s[j] - c2 * G2[n + j]);
    #pragma unroll
    for (int o = 32; o > 0; o >>= 1) mx = fmaxf(mx, __shfl_xor(mx, o));
    if ((tid & 63) == 0) wred[tid >> 6] = mx;
    __syncthreads();
    if (tid == 0) {
        mx = fmaxf(fmaxf(wred[0], wred[1]), fmaxf(wred[2], wred[3]));
        atomicMax(&Mkey[b], fkey_enc(mx));
    }
}

// ---------------- expk: P = bf16(exp(s - m)), L[b] += partial sum ----------
__global__ __launch_bounds__(256) void expk(
        const float* __restrict__ XG, const float* __restrict__ G2,
        const float* __restrict__ tarr, const unsigned* __restrict__ Mkey,
        unsigned short* __restrict__ P, float* __restrict__ L)
{
    const int b  = blockIdx.x >> 3;
    const int ch = blockIdx.x & 7;
    const int tid = threadIdx.x;
    float tt  = tarr[b] / 999.0f;
    float sig = 1.0f - tt;
    float inv = 1.0f / (sig * sig);
    float c1 = tt * inv, c2 = 0.5f * tt * tt * inv;
    float m = fkey_dec(Mkey[b]);
    const float* xg = XG + (size_t)b * NPAD;
    unsigned short* prow = P + (size_t)b * NPAD;
    __shared__ float wred[4];

    float sum = 0.f;
    int n0 = ch * 2560;
    for (int n = n0 + tid; n < n0 + 2560; n += 256) {
        float p = 0.f;
        if (n < N_SZ) { p = expf(c1 * xg[n] - c2 * G2[n] - m); sum += p; }
        prow[n] = f2bf(p);            // pad region -> exact 0
    }
    #pragma unroll
    for (int o = 32; o > 0; o >>= 1) sum += __shfl_xor(sum, o);
    if ((tid & 63) == 0) wred[tid >> 6] = sum;
    __syncthreads();
    if (tid == 0) atomicAdd(&L[b], wred[0] + wred[1] + wred[2] + wred[3]);
}

// ---------------- drift: Dacc_part[kc][b][d] = partial P.GhT^T ------------
// grid = 24 d-tiles * 40 K-chunks = 960; K-chunk 512 (16 steps of 32).
// Pure 2-operand bf16 GEMM via gl_lds of P [b][n] and GhT [d][n]
// (k-contiguous B rows -> no in-kernel transpose). Triple-buffered (48KB),
// counted vmcnt(4) + raw barrier, same schedule as scores.
__global__ __launch_bounds__(256) void drift_kernel(
        const unsigned short* __restrict__ GhT,
        const unsigned short* __restrict__ P,
        float* __restrict__ Dacc_part)
{
    __shared__ __align__(16) unsigned short Pt[3][128 * 32];
    __shared__ __align__(16) unsigned short Gt[3][128 * 32];

    const int tid = threadIdx.x;
    const int nt = blockIdx.x % 24;
    const int kc = blockIdx.x / 24;     // 0..39
    const int dbase = nt * 128;
    const int kcb = kc * 512;

    const int lane = tid & 63;
    const int wave = tid >> 6;
    const int mh = wave & 1;
    const int dh = wave >> 1;
    const int lm = lane & 15;
    const int qd = lane >> 4;

    int psrc[2], gsrc[2], dst[2];
    #pragma unroll
    for (int i = 0; i < 2; i++) {
        int o = (i * 256 + tid) * 16;
        int r = o >> 6;
        int j = (o >> 4) & 3;
        dst[i] = o;
        psrc[i] = r * NPAD + kcb + swz(r, j) * 8;
        gsrc[i] = (dbase + r) * NPAD + kcb + swz(r, j) * 8;
    }

    f32x4 acc[4][4];
    #pragma unroll
    for (int i = 0; i < 4; i++)
        #pragma unroll
        for (int j = 0; j < 4; j++)
            acc[i][j] = (f32x4){0.f, 0.f, 0.f, 0.f};

#define STAGE_D(ss, bb) do {                                              \
        int k0_ = (ss) * 32;                                              \
        gl_lds16(P   + psrc[0] + k0_, (char*)Pt[bb] + dst[0]);            \
        gl_lds16(P   + psrc[1] + k0_, (char*)Pt[bb] + dst[1]);            \
        gl_lds16(GhT + gsrc[0] + k0_, (char*)Gt[bb] + dst[0]);            \
        gl_lds16(GhT + gsrc[1] + k0_, (char*)Gt[bb] + dst[1]);            \
    } while (0)

    STAGE_D(0, 0);
    STAGE_D(1, 1);

    for (int s = 0; s < 16; s++) {
        if (s < 15) asm volatile("s_waitcnt vmcnt(4) lgkmcnt(0)" ::: "memory");
        else        asm volatile("s_waitcnt vmcnt(0) lgkmcnt(0)" ::: "memory");
        __builtin_amdgcn_sched_barrier(0);
        __builtin_amdgcn_s_barrier();
        __builtin_amdgcn_sched_barrier(0);

        const int bc = s % 3;
        if (s < 14) { STAGE_D(s + 2, (s + 2) % 3); }

        short8 af[4], bf8[4];
        #pragma unroll
        for (int mi = 0; mi < 4; mi++) {
            int r = mh * 64 + mi * 16 + lm;
            af[mi] = *(short8*)&Pt[bc][r * 32 + swz(r, qd) * 8];
        }
        #pragma unroll
        for (int ni = 0; ni < 4; ni++) {
            int r = dh * 64 + ni * 16 + lm;
            bf8[ni] = *(short8*)&Gt[bc][r * 32 + swz(r, qd) * 8];
        }
        #pragma unroll
        for (int mi = 0; mi < 4; mi++)
            #pragma unroll
            for (int ni = 0; ni < 4; ni++)
                acc[mi][ni] = __builtin_amdgcn_mfma_f32_16x16x32_bf16(af[mi], bf8[ni], acc[mi][ni], 0, 0, 0);
    }
#undef STAGE_D

    float* Dp = Dacc_part + (size_t)kc * BD;
    #pragma unroll
    for (int mi = 0; mi < 4; mi++)
        #pragma unroll
        for (int ni = 0; ni < 4; ni++) {
            int d = dbase + dh * 64 + ni * 16 + lm;
            #pragma unroll
            for (int i = 0; i < 4; i++) {
                int m = mh * 64 + mi * 16 + qd * 4 + i;
                Dp[(size_t)m * D_SZ + d] = acc[mi][ni][i];
            }
        }
}

// ---------------- epilogue: out = (sum_kc Dacc_part / L - x)/sig ----------
__global__ __launch_bounds__(256) void epilogue_kernel(
        const float* __restrict__ Dacc_part, const float* __restrict__ L,
        const float* __restrict__ x, const float* __restrict__ tarr,
        float* __restrict__ out)
{
    int i = (blockIdx.x * 256 + threadIdx.x) * 4;   // grid 384: covers BD
    int b = i / D_SZ;
    f32x4 s = (f32x4){0.f, 0.f, 0.f, 0.f};
    #pragma unroll
    for (int kc = 0; kc < KC_D; kc++)
        s += *(const f32x4*)(Dacc_part + (size_t)kc * BD + i);
    float tt = tarr[b] / 999.0f;
    float sig = 1.0f - tt;
    float invL = 1.0f / L[b];
    f32x4 xv = *(const f32x4*)(x + i);
    f32x4 o;
    #pragma unroll
    for (int j = 0; j < 4; j++) o[j] = (s[j] * invL - xv[j]) / sig;
    *(f32x4*)(out + i) = o;
}

extern "C" void kernel_launch(void* const* d_in, const int* in_sizes, int n_in,
                              void* d_out, int out_size, void* d_ws, size_t ws_size,
                              hipStream_t stream)
{
    const float* xt = (const float*)d_in[0];   // [128,3,32,32]
    const float* t  = (const float*)d_in[1];   // [128]
    const float* gt = (const float*)d_in[2];   // [20000,3,32,32]
    float* out = (float*)d_out;

    char* ws = (char*)d_ws;
    float*          XG_part  = (float*)(ws + 0);             // 4*BN*4   = 41943040
    float*          XG       = (float*)(ws + 41943040);      // BN*4     = 10485760
    float*          Dacc_part= (float*)(ws + 52428800);      // 40*BD*4  = 62914560
    float*          G2       = (float*)(ws + 115343360);     // 81920  } zeroed
    unsigned*       Mkey     = (unsigned*)(ws + 115425280);  //   512  } contiguous
    float*          L        = (float*)(ws + 115425792);     //   512  } 20736 f32
    unsigned short* Xhi      = (unsigned short*)(ws + 115426304); // 786432
    unsigned short* Xlo      = (unsigned short*)(ws + 116212736); // 786432
    unsigned short* P        = (unsigned short*)(ws + 116999168); // 5242880
    unsigned short* Ghi      = (unsigned short*)(ws + 122242048); // 125829120
    unsigned short* Glo      = (unsigned short*)(ws + 248071168); // 125829120
    unsigned short* GhT      = (unsigned short*)(ws + 373900288); // 125829120
    // total ~500 MB (< ws poison size 983 MB)

    zero_small    <<<    81, 256, 0, stream>>>(G2);          // G2+Mkey+L
    prep_x        <<<  1536, 256, 0, stream>>>(xt, Xhi, Xlo);
    prep_g        <<< 15360, 256, 0, stream>>>(gt, Ghi, Glo, GhT, G2);
    scores_kernel <<<  1252, 256, 0, stream>>>(Ghi, Glo, Xhi, Xlo, XG_part);
    sum4max       <<<  2560, 256, 0, stream>>>(XG_part, G2, t, XG, Mkey);
    expk          <<<  1024, 256, 0, stream>>>(XG, G2, t, Mkey, P, L);
    drift_kernel  <<<   960, 256, 0, stream>>>(GhT, P, Dacc_part);
    epilogue_kernel<<<  384, 256, 0, stream>>>(Dacc_part, L, xt, t, out);
}